// Round 1
// 1146.501 us; speedup vs baseline: 1.0968x; 1.0968x over previous
//
#include <hip/hip_runtime.h>

#define H 64
#define MAXW 256        // max windows (scan width)
#define WSH 10          // 1024 nodes per window -> W = ceil(200000/1024) = 196 <= MAXW
#define WNODES (1 << WSH)
#define BINCH 4096      // edges per k_bin block
#define BPT (BINCH / 256)

// ---------- window counting (LDS-aggregated; ~200 global atomics/block) ----------
__global__ __launch_bounds__(256) void k_wincount(const int* __restrict__ ei, int E,
                                                  int* __restrict__ winS, int* __restrict__ winD) {
    __shared__ int hs[MAXW], hd[MAXW];
    hs[threadIdx.x] = 0; hd[threadIdx.x] = 0;
    __syncthreads();
    int stride = gridDim.x * 256;
    for (int e = blockIdx.x * 256 + threadIdx.x; e < E; e += stride) {
        atomicAdd(&hs[ei[e] >> WSH], 1);
        atomicAdd(&hd[ei[E + e] >> WSH], 1);
    }
    __syncthreads();
    if (hs[threadIdx.x]) atomicAdd(&winS[threadIdx.x], hs[threadIdx.x]);
    if (hd[threadIdx.x]) atomicAdd(&winD[threadIdx.x], hd[threadIdx.x]);
}

// Single block: exclusive scan of both window-count arrays (MAXW wide, zero-padded).
__global__ void k_scan_win(const int* __restrict__ winS, const int* __restrict__ winD,
                           int* __restrict__ baseS, int* __restrict__ baseD,
                           int* __restrict__ curS, int* __restrict__ curD) {
    __shared__ int s[256];
    int tid = threadIdx.x;
    int v = winS[tid];
    s[tid] = v; __syncthreads();
    for (int off = 1; off < 256; off <<= 1) {
        int t = (tid >= off) ? s[tid - off] : 0; __syncthreads();
        s[tid] += t; __syncthreads();
    }
    int ex = s[tid] - v;
    baseS[tid] = ex; curS[tid] = ex;
    if (tid == 255) baseS[256] = s[255];
    __syncthreads();
    v = winD[tid];
    s[tid] = v; __syncthreads();
    for (int off = 1; off < 256; off <<= 1) {
        int t = (tid >= off) ? s[tid - off] : 0; __syncthreads();
        s[tid] += t; __syncthreads();
    }
    ex = s[tid] - v;
    baseD[tid] = ex; curD[tid] = ex;
    if (tid == 255) baseD[256] = s[255];
}

// ---------- bin: LDS counting-sort of a 4096-edge chunk by window, coalesced flush ----------
__global__ __launch_bounds__(256) void k_bin(const int* __restrict__ ei, int E,
                                             int* __restrict__ gcurS, int* __restrict__ gcurD,
                                             int2* __restrict__ bufS, int2* __restrict__ bufD) {
    __shared__ int hist[MAXW];
    __shared__ int lbase[MAXW];
    __shared__ int lcur[MAXW];
    __shared__ int gdelta[MAXW];
    __shared__ int2 rec[BINCH];
    __shared__ unsigned char wid[BINCH];
    __shared__ int sscan[256];

    int tid = threadIdx.x;
    int e0 = blockIdx.x * BINCH;
    int n = min(BINCH, E - e0);

    for (int dir = 0; dir < 2; ++dir) {
        int* gcur = dir ? gcurD : gcurS;
        int2* buf = dir ? bufD : bufS;
        hist[tid] = 0;
        __syncthreads();
        int kk[BPT], vv[BPT];
#pragma unroll
        for (int j = 0; j < BPT; ++j) {
            int idx = tid + j * 256;
            if (idx < n) {
                int e = e0 + idx;
                int a = ei[e], b = ei[E + e];
                kk[j] = dir ? b : a;
                vv[j] = dir ? a : b;
                atomicAdd(&hist[kk[j] >> WSH], 1);
            }
        }
        __syncthreads();
        {   // exclusive scan of hist
            int hv = hist[tid];
            sscan[tid] = hv; __syncthreads();
            for (int off = 1; off < 256; off <<= 1) {
                int t = (tid >= off) ? sscan[tid - off] : 0; __syncthreads();
                sscan[tid] += t; __syncthreads();
            }
            lbase[tid] = sscan[tid] - hv;
            lcur[tid] = lbase[tid];
        }
        __syncthreads();
#pragma unroll
        for (int j = 0; j < BPT; ++j) {
            int idx = tid + j * 256;
            if (idx < n) {
                int w = kk[j] >> WSH;
                int p = atomicAdd(&lcur[w], 1);
                rec[p] = make_int2(kk[j], vv[j]);
                wid[p] = (unsigned char)w;
            }
        }
        __syncthreads();
        {   // reserve one contiguous global chunk per non-empty window
            int c = hist[tid];
            int g = c ? atomicAdd(&gcur[tid], c) : 0;
            gdelta[tid] = g - lbase[tid];
        }
        __syncthreads();
        for (int j = tid; j < n; j += 256) {   // coalesced flush (runs sorted by window)
            int w = wid[j];
            int2 r = rec[j];
            *(long long*)&buf[gdelta[w] + j] = *(long long*)&r;
        }
        __syncthreads();
    }
}

// ---------- per-window degree histogram (LDS table, coalesced deg write) ----------
__global__ __launch_bounds__(256) void k_degwin(const int2* __restrict__ bufS,
                                                const int2* __restrict__ bufD,
                                                const int* __restrict__ baseS,
                                                const int* __restrict__ baseD,
                                                int* __restrict__ degS, int* __restrict__ degD,
                                                int Ns, int Nd, int W) {
    __shared__ int h[WNODES];
    int b = blockIdx.x;
    int dir = (b >= W) ? 1 : 0;
    int w = dir ? b - W : b;
    const int2* buf = dir ? bufD : bufS;
    const int* base = dir ? baseD : baseS;
    int* deg = dir ? degD : degS;
    int N = dir ? Nd : Ns;
    int lo = w << WSH;
    int hi = min(lo + WNODES, N);
    for (int i = threadIdx.x; i < WNODES; i += 256) h[i] = 0;
    __syncthreads();
    int beg = base[w], end = base[w + 1];
    for (int r = beg + threadIdx.x; r < end; r += 256)
        atomicAdd(&h[buf[r].x - lo], 1);
    __syncthreads();
    for (int i = lo + threadIdx.x; i < hi; i += 256) deg[i] = h[i - lo];
}

// ---------- per-window CSR scatter (LDS cursors; writes confined to ~80KB segment) ----------
__global__ __launch_bounds__(256) void k_scatwin(const int2* __restrict__ bufS,
                                                 const int2* __restrict__ bufD,
                                                 const int* __restrict__ baseS,
                                                 const int* __restrict__ baseD,
                                                 const int* __restrict__ rpS,
                                                 const int* __restrict__ rpD,
                                                 int* __restrict__ colS, int* __restrict__ colD,
                                                 int Ns, int Nd, int W) {
    __shared__ int cur[WNODES];
    int b = blockIdx.x;
    int dir = (b >= W) ? 1 : 0;
    int w = dir ? b - W : b;
    const int2* buf = dir ? bufD : bufS;
    const int* base = dir ? baseD : baseS;
    const int* rp = dir ? rpD : rpS;
    int* col = dir ? colD : colS;
    int N = dir ? Nd : Ns;
    int lo = w << WSH;
    int hi = min(lo + WNODES, N);
    for (int i = lo + threadIdx.x; i < hi; i += 256) cur[i - lo] = rp[i];
    __syncthreads();
    int beg = base[w], end = base[w + 1];
    for (int r = beg + threadIdx.x; r < end; r += 256) {
        int2 rc = buf[r];
        int p = atomicAdd(&cur[rc.x - lo], 1);
        col[p] = rc.y;
    }
}

// ---------- deg -> rp scans ----------
__global__ void k_chunk_sums(const int* __restrict__ deg, int n, int* __restrict__ bsum) {
    __shared__ int s[256];
    int tid = threadIdx.x;
    int base = blockIdx.x * 1024 + tid * 4;
    int t = 0;
#pragma unroll
    for (int j = 0; j < 4; ++j) { int i = base + j; if (i < n) t += deg[i]; }
    s[tid] = t; __syncthreads();
    for (int off = 128; off > 0; off >>= 1) {
        if (tid < off) s[tid] += s[tid + off];
        __syncthreads();
    }
    if (tid == 0) bsum[blockIdx.x] = s[0];
}

__global__ void k_scan_bsums(int* __restrict__ bsum, int nb, int* __restrict__ rp, int n) {
    __shared__ int s[256];
    int tid = threadIdx.x;
    int v = (tid < nb) ? bsum[tid] : 0;
    s[tid] = v; __syncthreads();
    for (int off = 1; off < 256; off <<= 1) {
        int t = (tid >= off) ? s[tid - off] : 0; __syncthreads();
        s[tid] += t; __syncthreads();
    }
    if (tid < nb) bsum[tid] = s[tid] - v;
    if (tid == 255) rp[n] = s[255];
}

__global__ void k_scan_final(const int* __restrict__ deg, int n,
                             const int* __restrict__ bsum, int* __restrict__ rp) {
    __shared__ int s[256];
    int tid = threadIdx.x;
    int base = blockIdx.x * 1024 + tid * 4;
    int v[4]; int t = 0;
#pragma unroll
    for (int j = 0; j < 4; ++j) { int i = base + j; v[j] = (i < n) ? deg[i] : 0; t += v[j]; }
    s[tid] = t; __syncthreads();
    for (int off = 1; off < 256; off <<= 1) {
        int x = (tid >= off) ? s[tid - off] : 0; __syncthreads();
        s[tid] += x; __syncthreads();
    }
    int excl = s[tid] - t + bsum[blockIdx.x];
#pragma unroll
    for (int j = 0; j < 4; ++j) { int i = base + j; if (i < n) rp[i] = excl; excl += v[j]; }
}

// ---------- feature init: 4 nodes per 256-thread block ----------
__global__ __launch_bounds__(256) void k_init_x(const int* __restrict__ uid, const int* __restrict__ rid,
                         const float* __restrict__ recipe_x,
                         const float* __restrict__ user_emb, const float* __restrict__ recipe_emb,
                         const float* __restrict__ lin_w, const float* __restrict__ lin_b,
                         float* __restrict__ x_user, float* __restrict__ x_recipe,
                         int Nu, int Nr) {
    int n = blockIdx.x * 4 + (threadIdx.x >> 6);
    int h = threadIdx.x & 63;
    if (n < Nr) {
        float o = lin_b[h];
#pragma unroll
        for (int k = 0; k < 10; ++k)   // recipe_x addr wave-uniform -> broadcast load
            o = fmaf(recipe_x[(size_t)n * 10 + k], lin_w[k * H + h], o);
        o += recipe_emb[(size_t)rid[n] * H + h];
        x_recipe[(size_t)n * H + h] = o;
    }
    if (n < Nu) {
        x_user[(size_t)n * H + h] = user_emb[(size_t)uid[n] * H + h];
    }
}

// ---------- SAGE layer (dual direction in one launch) ----------
// Gather mapping: one 16-lane group per dst node -> 4 INDEPENDENT latency chains
// per wave (was: 4 nodes processed serially, one chain). Each group's 16 lanes
// cover the 64-float row (float4/lane); a wave-wide load still moves 4x256B=1KB
// coalesced. Mean is lane-local (no cross-group shfl). 32-bit gather offsets
// ((r<<4)+c float4 index; byte offset < 52MB) avoid 64-bit addr mul in the loop.
// Epilogue unchanged: one Wl/Wr 256B L1 load per k serves 4 nodes; only
// o0..o3+wl+wr live. VGPR target <=64 for 8 waves/SIMD (launch_bounds(256,8)).
template <bool RELU>
__global__ __launch_bounds__(256, 8) void k_sage2(
    const float* __restrict__ xsA, const float* __restrict__ xdA,
    const int* __restrict__ rpA, const int* __restrict__ colA,
    const float* __restrict__ WlA, const float* __restrict__ blA,
    const float* __restrict__ WrA, float* __restrict__ outA, int ndA, int nbA,
    const float* __restrict__ xsB, const float* __restrict__ xdB,
    const int* __restrict__ rpB, const int* __restrict__ colB,
    const float* __restrict__ WlB, const float* __restrict__ blB,
    const float* __restrict__ WrB, float* __restrict__ outB, int ndB) {
    const float* x_src; const float* x_dst; const int* rp; const int* col;
    const float* Wl; const float* bl; const float* Wr; float* out;
    int n_dst, bid;
    if (blockIdx.x < (unsigned)nbA) {
        x_src = xsA; x_dst = xdA; rp = rpA; col = colA;
        Wl = WlA; bl = blA; Wr = WrA; out = outA; n_dst = ndA; bid = blockIdx.x;
    } else {
        x_src = xsB; x_dst = xdB; rp = rpB; col = colB;
        Wl = WlB; bl = blB; Wr = WrB; out = outB; n_dst = ndB; bid = blockIdx.x - nbA;
    }

    int wave = threadIdx.x >> 6, lane = threadIdx.x & 63;
    int c = lane & 15, g = lane >> 4;          // group g owns node n0+g
    int n0 = (bid * 4 + wave) * 4;
    __shared__ float sm[4][4][H];   // [wave][node][feature] mean
    __shared__ float sx[4][4][H];   // [wave][node][feature] x_dst

    int n = n0 + g;
    if (n < n_dst) {
        const float4* xs = (const float4*)x_src;
        // x_dst row: issued first, overlaps rp/col/gather latency
        float4 xd = ((const float4*)x_dst)[(n << 4) + c];
        int beg = rp[n], end = rp[n + 1];
        float4 a0 = make_float4(0.f, 0.f, 0.f, 0.f);
        float4 a1 = a0, a2 = a0, a3 = a0;
        int e = beg;
        for (; e + 3 < end; e += 4) {
            int r0 = col[e];
            int r1 = col[e + 1];
            int r2 = col[e + 2];
            int r3 = col[e + 3];
            float4 v0 = xs[(r0 << 4) + c];
            float4 v1 = xs[(r1 << 4) + c];
            float4 v2 = xs[(r2 << 4) + c];
            float4 v3 = xs[(r3 << 4) + c];
            a0.x += v0.x; a0.y += v0.y; a0.z += v0.z; a0.w += v0.w;
            a1.x += v1.x; a1.y += v1.y; a1.z += v1.z; a1.w += v1.w;
            a2.x += v2.x; a2.y += v2.y; a2.z += v2.z; a2.w += v2.w;
            a3.x += v3.x; a3.y += v3.y; a3.z += v3.z; a3.w += v3.w;
        }
        for (; e < end; ++e) {
            int r = col[e];
            float4 v = xs[(r << 4) + c];
            a0.x += v.x; a0.y += v.y; a0.z += v.z; a0.w += v.w;
        }
        float inv = 1.0f / fmaxf((float)(end - beg), 1.0f);
        float4 mv;
        mv.x = ((a0.x + a1.x) + (a2.x + a3.x)) * inv;
        mv.y = ((a0.y + a1.y) + (a2.y + a3.y)) * inv;
        mv.z = ((a0.z + a1.z) + (a2.z + a3.z)) * inv;
        mv.w = ((a0.w + a1.w) + (a2.w + a3.w)) * inv;
        *((float4*)&sm[wave][g][c * 4]) = mv;
        *((float4*)&sx[wave][g][c * 4]) = xd;
    }
    __syncthreads();   // one barrier per 16 nodes

    if (n0 < n_dst) {
        float bb = bl[lane];
        float o0 = bb, o1 = bb, o2 = bb, o3 = bb;
        const float* m = &sm[wave][0][0];   // 4 rows of H, contiguous
        const float* x = &sx[wave][0][0];
#pragma unroll 4
        for (int k = 0; k < H; ++k) {
            float wl = Wl[k * H + lane];    // one 256B L1 load serves 4 nodes
            float wr = Wr[k * H + lane];
            o0 = fmaf(m[0 * H + k], wl, o0); o0 = fmaf(x[0 * H + k], wr, o0);
            o1 = fmaf(m[1 * H + k], wl, o1); o1 = fmaf(x[1 * H + k], wr, o1);
            o2 = fmaf(m[2 * H + k], wl, o2); o2 = fmaf(x[2 * H + k], wr, o2);
            o3 = fmaf(m[3 * H + k], wl, o3); o3 = fmaf(x[3 * H + k], wr, o3);
        }
        if (RELU) {
            o0 = fmaxf(o0, 0.f); o1 = fmaxf(o1, 0.f);
            o2 = fmaxf(o2, 0.f); o3 = fmaxf(o3, 0.f);
        }
        out[(size_t)n0 * H + lane] = o0;
        if (n0 + 1 < n_dst) out[(size_t)(n0 + 1) * H + lane] = o1;
        if (n0 + 2 < n_dst) out[(size_t)(n0 + 2) * H + lane] = o2;
        if (n0 + 3 < n_dst) out[(size_t)(n0 + 3) * H + lane] = o3;
    }
}

// ---------- classifier ----------
__global__ __launch_bounds__(256) void k_dot(const float* __restrict__ xu,
                                             const float* __restrict__ xr,
                                             const int* __restrict__ eli,
                                             float* __restrict__ out, int L) {
    long long w = (blockIdx.x * (long long)blockDim.x + threadIdx.x) >> 6;
    int lane = threadIdx.x & 63;
    int c = lane & 15, g = lane >> 4;
    long long e = w * 4 + g;
    if (e >= L) return;
    int a = eli[e], b = eli[(long long)L + e];
    float4 u = *((const float4*)(xu + (size_t)a * H) + c);
    float4 r = *((const float4*)(xr + (size_t)b * H) + c);
    float p = u.x * r.x;
    p = fmaf(u.y, r.y, p);
    p = fmaf(u.z, r.z, p);
    p = fmaf(u.w, r.w, p);
#pragma unroll
    for (int off = 1; off < 16; off <<= 1) p += __shfl_xor(p, off);
    if (c == 0) out[e] = p;
}

extern "C" void kernel_launch(void* const* d_in, const int* in_sizes, int n_in,
                              void* d_out, int out_size, void* d_ws, size_t ws_size,
                              hipStream_t stream) {
    const int*   uid        = (const int*)d_in[0];
    const int*   rid        = (const int*)d_in[1];
    const float* recipe_x   = (const float*)d_in[2];
    const int*   ei         = (const int*)d_in[3];
    const int*   eli        = (const int*)d_in[4];
    const float* user_emb   = (const float*)d_in[5];
    const float* recipe_emb = (const float*)d_in[6];
    const float* lin_w      = (const float*)d_in[7];
    const float* lin_b      = (const float*)d_in[8];
    const float* Wl         = (const float*)d_in[9];
    const float* bl         = (const float*)d_in[10];
    const float* Wr         = (const float*)d_in[11];

    const int Nu = in_sizes[0], Nr = in_sizes[1];
    const int E = in_sizes[3] / 2, L = in_sizes[4] / 2;
    const int nmax = (Nu > Nr) ? Nu : Nr;
    const int W = ((nmax - 1) >> WSH) + 1;   // 196 for N=200000

    char* ws = (char*)d_ws;
    size_t off = 0;
    auto alloc = [&](size_t bytes) -> char* {
        char* p = ws + off;
        off += (bytes + 255) & ~(size_t)255;
        return p;
    };
    float* x_user   = (float*)alloc((size_t)Nu * H * 4);
    float* x_recipe = (float*)alloc((size_t)Nr * H * 4);
    // overlay: y buffers (needed from sage on) share space with bin buffers (dead by then)
    size_t ybytes  = ((size_t)Nu + Nr) * H * 4;
    size_t bbytes  = (size_t)E * 8 * 2;
    char* region   = alloc(ybytes > bbytes ? ybytes : bbytes);
    float* y_user   = (float*)region;
    float* y_recipe = (float*)(region + (size_t)Nu * H * 4);
    int2* bufS = (int2*)region;
    int2* bufD = (int2*)(region + (size_t)E * 8);
    int* deg_src = (int*)alloc((size_t)Nu * 4);
    int* deg_dst = (int*)alloc((size_t)Nr * 4);
    int* rp_src  = (int*)alloc((size_t)(Nu + 1) * 4);
    int* rp_dst  = (int*)alloc((size_t)(Nr + 1) * 4);
    int* col_src = (int*)alloc((size_t)E * 4);
    int* col_dst = (int*)alloc((size_t)E * 4);
    int* winS  = (int*)alloc(MAXW * 4);      // winS..winD adjacent: one memset
    int* winD  = (int*)alloc(MAXW * 4);
    int* baseS = (int*)alloc((MAXW + 1) * 4);
    int* baseD = (int*)alloc((MAXW + 1) * 4);
    int* curS  = (int*)alloc(MAXW * 4);
    int* curD  = (int*)alloc(MAXW * 4);
    int* bsum  = (int*)alloc(4096);
    (void)ws_size; (void)n_in; (void)out_size;

    // zero window counters (ws is poisoned 0xAA)
    hipMemsetAsync(winS, 0, (size_t)2 * MAXW * 4, stream);

    // CSR build: count -> scan -> bin -> per-window deg -> rp -> per-window scatter
    k_wincount<<<1024, 256, 0, stream>>>(ei, E, winS, winD);
    k_scan_win<<<1, 256, 0, stream>>>(winS, winD, baseS, baseD, curS, curD);
    k_bin<<<(E + BINCH - 1) / BINCH, 256, 0, stream>>>(ei, E, curS, curD, bufS, bufD);
    k_degwin<<<2 * W, 256, 0, stream>>>(bufS, bufD, baseS, baseD, deg_src, deg_dst, Nu, Nr, W);

    int nb_s = (Nu + 1023) / 1024, nb_d = (Nr + 1023) / 1024;
    k_chunk_sums<<<nb_s, 256, 0, stream>>>(deg_src, Nu, bsum);
    k_scan_bsums<<<1, 256, 0, stream>>>(bsum, nb_s, rp_src, Nu);
    k_scan_final<<<nb_s, 256, 0, stream>>>(deg_src, Nu, bsum, rp_src);
    k_chunk_sums<<<nb_d, 256, 0, stream>>>(deg_dst, Nr, bsum);
    k_scan_bsums<<<1, 256, 0, stream>>>(bsum, nb_d, rp_dst, Nr);
    k_scan_final<<<nb_d, 256, 0, stream>>>(deg_dst, Nr, bsum, rp_dst);

    k_scatwin<<<2 * W, 256, 0, stream>>>(bufS, bufD, baseS, baseD, rp_src, rp_dst,
                                         col_src, col_dst, Nu, Nr, W);

    // initial features
    k_init_x<<<(nmax + 3) / 4, 256, 0, stream>>>(uid, rid, recipe_x, user_emb, recipe_emb,
                                                 lin_w, lin_b, x_user, x_recipe, Nu, Nr);

    int nbR = (Nr + 15) / 16, nbU = (Nu + 15) / 16;
    // layer 0 (+ReLU): both directions in one launch
    k_sage2<true><<<nbR + nbU, 256, 0, stream>>>(
        x_user, x_recipe, rp_dst, col_dst, Wl + 0 * H * H, bl + 0 * H, Wr + 0 * H * H, y_recipe, Nr, nbR,
        x_recipe, x_user, rp_src, col_src, Wl + 1 * H * H, bl + 1 * H, Wr + 1 * H * H, y_user, Nu);
    // layer 1 (no ReLU)
    k_sage2<false><<<nbR + nbU, 256, 0, stream>>>(
        y_user, y_recipe, rp_dst, col_dst, Wl + 2 * H * H, bl + 2 * H, Wr + 2 * H * H, x_recipe, Nr, nbR,
        y_recipe, y_user, rp_src, col_src, Wl + 3 * H * H, bl + 3 * H, Wr + 3 * H * H, x_user, Nu);

    // classifier
    long long nwaves = ((long long)L + 3) / 4;
    long long nblk = (nwaves + 3) / 4;
    k_dot<<<(int)nblk, 256, 0, stream>>>(x_user, x_recipe, eli, (float*)d_out, L);
}

// Round 2
// 1124.010 us; speedup vs baseline: 1.1188x; 1.0200x over previous
//
#include <hip/hip_runtime.h>

#define H 64
#define MAXW 256        // max windows (scan width)
#define WSH 10          // 1024 nodes per window -> W = ceil(200000/1024) = 196 <= MAXW
#define WNODES (1 << WSH)
#define BINCH 4096      // edges per k_bin block
#define BPT (BINCH / 256)

#define ADD4(a, v) { a.x += v.x; a.y += v.y; a.z += v.z; a.w += v.w; }

// ---------- window counting (LDS-aggregated; ~200 global atomics/block) ----------
__global__ __launch_bounds__(256) void k_wincount(const int* __restrict__ ei, int E,
                                                  int* __restrict__ winS, int* __restrict__ winD) {
    __shared__ int hs[MAXW], hd[MAXW];
    hs[threadIdx.x] = 0; hd[threadIdx.x] = 0;
    __syncthreads();
    int stride = gridDim.x * 256;
    for (int e = blockIdx.x * 256 + threadIdx.x; e < E; e += stride) {
        atomicAdd(&hs[ei[e] >> WSH], 1);
        atomicAdd(&hd[ei[E + e] >> WSH], 1);
    }
    __syncthreads();
    if (hs[threadIdx.x]) atomicAdd(&winS[threadIdx.x], hs[threadIdx.x]);
    if (hd[threadIdx.x]) atomicAdd(&winD[threadIdx.x], hd[threadIdx.x]);
}

// Single block: exclusive scan of both window-count arrays (MAXW wide, zero-padded).
__global__ void k_scan_win(const int* __restrict__ winS, const int* __restrict__ winD,
                           int* __restrict__ baseS, int* __restrict__ baseD,
                           int* __restrict__ curS, int* __restrict__ curD) {
    __shared__ int s[256];
    int tid = threadIdx.x;
    int v = winS[tid];
    s[tid] = v; __syncthreads();
    for (int off = 1; off < 256; off <<= 1) {
        int t = (tid >= off) ? s[tid - off] : 0; __syncthreads();
        s[tid] += t; __syncthreads();
    }
    int ex = s[tid] - v;
    baseS[tid] = ex; curS[tid] = ex;
    if (tid == 255) baseS[256] = s[255];
    __syncthreads();
    v = winD[tid];
    s[tid] = v; __syncthreads();
    for (int off = 1; off < 256; off <<= 1) {
        int t = (tid >= off) ? s[tid - off] : 0; __syncthreads();
        s[tid] += t; __syncthreads();
    }
    ex = s[tid] - v;
    baseD[tid] = ex; curD[tid] = ex;
    if (tid == 255) baseD[256] = s[255];
}

// ---------- bin: LDS counting-sort of a 4096-edge chunk by window, coalesced flush ----------
__global__ __launch_bounds__(256) void k_bin(const int* __restrict__ ei, int E,
                                             int* __restrict__ gcurS, int* __restrict__ gcurD,
                                             int2* __restrict__ bufS, int2* __restrict__ bufD) {
    __shared__ int hist[MAXW];
    __shared__ int lbase[MAXW];
    __shared__ int lcur[MAXW];
    __shared__ int gdelta[MAXW];
    __shared__ int2 rec[BINCH];
    __shared__ unsigned char wid[BINCH];
    __shared__ int sscan[256];

    int tid = threadIdx.x;
    int e0 = blockIdx.x * BINCH;
    int n = min(BINCH, E - e0);

    for (int dir = 0; dir < 2; ++dir) {
        int* gcur = dir ? gcurD : gcurS;
        int2* buf = dir ? bufD : bufS;
        hist[tid] = 0;
        __syncthreads();
        int kk[BPT], vv[BPT];
#pragma unroll
        for (int j = 0; j < BPT; ++j) {
            int idx = tid + j * 256;
            if (idx < n) {
                int e = e0 + idx;
                int a = ei[e], b = ei[E + e];
                kk[j] = dir ? b : a;
                vv[j] = dir ? a : b;
                atomicAdd(&hist[kk[j] >> WSH], 1);
            }
        }
        __syncthreads();
        {   // exclusive scan of hist
            int hv = hist[tid];
            sscan[tid] = hv; __syncthreads();
            for (int off = 1; off < 256; off <<= 1) {
                int t = (tid >= off) ? sscan[tid - off] : 0; __syncthreads();
                sscan[tid] += t; __syncthreads();
            }
            lbase[tid] = sscan[tid] - hv;
            lcur[tid] = lbase[tid];
        }
        __syncthreads();
#pragma unroll
        for (int j = 0; j < BPT; ++j) {
            int idx = tid + j * 256;
            if (idx < n) {
                int w = kk[j] >> WSH;
                int p = atomicAdd(&lcur[w], 1);
                rec[p] = make_int2(kk[j], vv[j]);
                wid[p] = (unsigned char)w;
            }
        }
        __syncthreads();
        {   // reserve one contiguous global chunk per non-empty window
            int c = hist[tid];
            int g = c ? atomicAdd(&gcur[tid], c) : 0;
            gdelta[tid] = g - lbase[tid];
        }
        __syncthreads();
        for (int j = tid; j < n; j += 256) {   // coalesced flush (runs sorted by window)
            int w = wid[j];
            int2 r = rec[j];
            *(long long*)&buf[gdelta[w] + j] = *(long long*)&r;
        }
        __syncthreads();
    }
}

// ---------- fused per-window CSR build: histogram -> LDS scan -> rp -> scatter ----------
// baseS[w] is ALREADY the global col offset of window w (buf and col share the
// window-major layout), so rp[i] = base[w] + in-window exclusive scan. This
// replaces k_degwin + 3-kernel global scan x2 + k_scatwin (6 dispatches + deg
// global traffic) with one kernel.
__global__ __launch_bounds__(256) void k_build_win(const int2* __restrict__ bufS,
                                                   const int2* __restrict__ bufD,
                                                   const int* __restrict__ baseS,
                                                   const int* __restrict__ baseD,
                                                   int* __restrict__ rpS, int* __restrict__ rpD,
                                                   int* __restrict__ colS, int* __restrict__ colD,
                                                   int Ns, int Nd, int W) {
    __shared__ int h[WNODES];
    __shared__ int sscan[256];
    int b = blockIdx.x, tid = threadIdx.x;
    int dir = (b >= W) ? 1 : 0;
    int w = dir ? b - W : b;
    const int2* buf = dir ? bufD : bufS;
    const int* base = dir ? baseD : baseS;
    int* rp = dir ? rpD : rpS;
    int* col = dir ? colD : colS;
    int N = dir ? Nd : Ns;
    int lo = w << WSH;
    int hi = min(lo + WNODES, N);

    for (int i = tid; i < WNODES; i += 256) h[i] = 0;
    __syncthreads();
    int beg = base[w], end = base[w + 1];
    for (int r = beg + tid; r < end; r += 256)
        atomicAdd(&h[buf[r].x - lo], 1);
    __syncthreads();

    // exclusive scan of h[0..1023] (4 elems/thread + 256-wide LDS scan)
    int i0 = tid * 4;
    int v0 = h[i0], v1 = h[i0 + 1], v2 = h[i0 + 2], v3 = h[i0 + 3];
    int t = v0 + v1 + v2 + v3;
    sscan[tid] = t; __syncthreads();
    for (int off = 1; off < 256; off <<= 1) {
        int x = (tid >= off) ? sscan[tid - off] : 0; __syncthreads();
        sscan[tid] += x; __syncthreads();
    }
    int e0 = sscan[tid] - t;
    int e1 = e0 + v0, e2 = e1 + v1, e3 = e2 + v2;
    h[i0] = e0; h[i0 + 1] = e1; h[i0 + 2] = e2; h[i0 + 3] = e3;  // cursors
    int gi = lo + i0;
    if (gi < hi) rp[gi] = beg + e0;
    if (gi + 1 < hi) rp[gi + 1] = beg + e1;
    if (gi + 2 < hi) rp[gi + 2] = beg + e2;
    if (gi + 3 < hi) rp[gi + 3] = beg + e3;
    if (tid == 255 && hi == N) rp[N] = beg + sscan[255];
    __syncthreads();

    for (int r = beg + tid; r < end; r += 256) {
        int2 rc = buf[r];
        int p = atomicAdd(&h[rc.x - lo], 1);
        col[beg + p] = rc.y;
    }
}

// ---------- feature init: 4 nodes per 256-thread block ----------
__global__ __launch_bounds__(256) void k_init_x(const int* __restrict__ uid, const int* __restrict__ rid,
                         const float* __restrict__ recipe_x,
                         const float* __restrict__ user_emb, const float* __restrict__ recipe_emb,
                         const float* __restrict__ lin_w, const float* __restrict__ lin_b,
                         float* __restrict__ x_user, float* __restrict__ x_recipe,
                         int Nu, int Nr) {
    int n = blockIdx.x * 4 + (threadIdx.x >> 6);
    int h = threadIdx.x & 63;
    if (n < Nr) {
        float o = lin_b[h];
#pragma unroll
        for (int k = 0; k < 10; ++k)   // recipe_x addr wave-uniform -> broadcast load
            o = fmaf(recipe_x[(size_t)n * 10 + k], lin_w[k * H + h], o);
        o += recipe_emb[(size_t)rid[n] * H + h];
        x_recipe[(size_t)n * H + h] = o;
    }
    if (n < Nu) {
        x_user[(size_t)n * H + h] = user_emb[(size_t)uid[n] * H + h];
    }
}

// ---------- SAGE layer (dual direction in one launch) ----------
// One 16-lane group per dst node; 8 gathers in flight per group (48 loads in
// flight per SIMD at 6 waves). sm/sx are WAVE-PRIVATE ([wave][j] only read by
// wave `wave`), so no __syncthreads: s_waitcnt lgkmcnt(0) + sched_barrier(0)
// orders the cross-lane LDS handoff within the wave (DS pipe is in-order per
// wave). Each wave progresses independently -> no 16-node max-degree coupling.
// 32-bit gather offsets ((r<<4)+c float4 index; byte offset < 52MB).
template <bool RELU>
__global__ __launch_bounds__(256, 6) void k_sage2(
    const float* __restrict__ xsA, const float* __restrict__ xdA,
    const int* __restrict__ rpA, const int* __restrict__ colA,
    const float* __restrict__ WlA, const float* __restrict__ blA,
    const float* __restrict__ WrA, float* __restrict__ outA, int ndA, int nbA,
    const float* __restrict__ xsB, const float* __restrict__ xdB,
    const int* __restrict__ rpB, const int* __restrict__ colB,
    const float* __restrict__ WlB, const float* __restrict__ blB,
    const float* __restrict__ WrB, float* __restrict__ outB, int ndB) {
    const float* x_src; const float* x_dst; const int* rp; const int* col;
    const float* Wl; const float* bl; const float* Wr; float* out;
    int n_dst, bid;
    if (blockIdx.x < (unsigned)nbA) {
        x_src = xsA; x_dst = xdA; rp = rpA; col = colA;
        Wl = WlA; bl = blA; Wr = WrA; out = outA; n_dst = ndA; bid = blockIdx.x;
    } else {
        x_src = xsB; x_dst = xdB; rp = rpB; col = colB;
        Wl = WlB; bl = blB; Wr = WrB; out = outB; n_dst = ndB; bid = blockIdx.x - nbA;
    }

    int wave = threadIdx.x >> 6, lane = threadIdx.x & 63;
    int c = lane & 15, g = lane >> 4;          // group g owns node n0+g
    int n0 = (bid * 4 + wave) * 4;
    __shared__ float sm[4][4][H];   // [wave][node][feature] mean   (wave-private)
    __shared__ float sx[4][4][H];   // [wave][node][feature] x_dst  (wave-private)

    int n = n0 + g;
    if (n < n_dst) {
        const float4* xs = (const float4*)x_src;
        // x_dst row: issued first, overlaps rp/col/gather latency
        float4 xd = ((const float4*)x_dst)[(n << 4) + c];
        int beg = rp[n], end = rp[n + 1];
        float4 a0 = make_float4(0.f, 0.f, 0.f, 0.f);
        float4 a1 = a0, a2 = a0, a3 = a0;
        int e = beg;
        for (; e + 7 < end; e += 8) {           // 8 loads in flight per group
            int r0 = col[e];
            int r1 = col[e + 1];
            int r2 = col[e + 2];
            int r3 = col[e + 3];
            int r4 = col[e + 4];
            int r5 = col[e + 5];
            int r6 = col[e + 6];
            int r7 = col[e + 7];
            float4 v0 = xs[(r0 << 4) + c];
            float4 v1 = xs[(r1 << 4) + c];
            float4 v2 = xs[(r2 << 4) + c];
            float4 v3 = xs[(r3 << 4) + c];
            float4 v4 = xs[(r4 << 4) + c];
            float4 v5 = xs[(r5 << 4) + c];
            float4 v6 = xs[(r6 << 4) + c];
            float4 v7 = xs[(r7 << 4) + c];
            ADD4(a0, v0); ADD4(a1, v1); ADD4(a2, v2); ADD4(a3, v3);
            ADD4(a0, v4); ADD4(a1, v5); ADD4(a2, v6); ADD4(a3, v7);
        }
        for (; e + 3 < end; e += 4) {
            int r0 = col[e];
            int r1 = col[e + 1];
            int r2 = col[e + 2];
            int r3 = col[e + 3];
            float4 v0 = xs[(r0 << 4) + c];
            float4 v1 = xs[(r1 << 4) + c];
            float4 v2 = xs[(r2 << 4) + c];
            float4 v3 = xs[(r3 << 4) + c];
            ADD4(a0, v0); ADD4(a1, v1); ADD4(a2, v2); ADD4(a3, v3);
        }
        for (; e < end; ++e) {
            int r = col[e];
            float4 v = xs[(r << 4) + c];
            ADD4(a0, v);
        }
        float inv = 1.0f / fmaxf((float)(end - beg), 1.0f);
        float4 mv;
        mv.x = ((a0.x + a1.x) + (a2.x + a3.x)) * inv;
        mv.y = ((a0.y + a1.y) + (a2.y + a3.y)) * inv;
        mv.z = ((a0.z + a1.z) + (a2.z + a3.z)) * inv;
        mv.w = ((a0.w + a1.w) + (a2.w + a3.w)) * inv;
        *((float4*)&sm[wave][g][c * 4]) = mv;
        *((float4*)&sx[wave][g][c * 4]) = xd;
    }
    // wave-local LDS handoff: drain DS writes, forbid reordering. No s_barrier.
    asm volatile("s_waitcnt lgkmcnt(0)" ::: "memory");
    __builtin_amdgcn_sched_barrier(0);

    if (n0 < n_dst) {
        float bb = bl[lane];
        float o0 = bb, o1 = bb, o2 = bb, o3 = bb;
        const float* m = &sm[wave][0][0];   // 4 rows of H, contiguous
        const float* x = &sx[wave][0][0];
#pragma unroll 4
        for (int k = 0; k < H; ++k) {
            float wl = Wl[k * H + lane];    // one 256B L1 load serves 4 nodes
            float wr = Wr[k * H + lane];
            o0 = fmaf(m[0 * H + k], wl, o0); o0 = fmaf(x[0 * H + k], wr, o0);
            o1 = fmaf(m[1 * H + k], wl, o1); o1 = fmaf(x[1 * H + k], wr, o1);
            o2 = fmaf(m[2 * H + k], wl, o2); o2 = fmaf(x[2 * H + k], wr, o2);
            o3 = fmaf(m[3 * H + k], wl, o3); o3 = fmaf(x[3 * H + k], wr, o3);
        }
        if (RELU) {
            o0 = fmaxf(o0, 0.f); o1 = fmaxf(o1, 0.f);
            o2 = fmaxf(o2, 0.f); o3 = fmaxf(o3, 0.f);
        }
        out[(size_t)n0 * H + lane] = o0;
        if (n0 + 1 < n_dst) out[(size_t)(n0 + 1) * H + lane] = o1;
        if (n0 + 2 < n_dst) out[(size_t)(n0 + 2) * H + lane] = o2;
        if (n0 + 3 < n_dst) out[(size_t)(n0 + 3) * H + lane] = o3;
    }
}

// ---------- classifier: 2 edges per 16-lane group (4 gathers in flight) ----------
__global__ __launch_bounds__(256) void k_dot(const float* __restrict__ xu,
                                             const float* __restrict__ xr,
                                             const int* __restrict__ eli,
                                             float* __restrict__ out, int L) {
    long long wv = (blockIdx.x * 256LL + threadIdx.x) >> 6;
    int lane = threadIdx.x & 63;
    int c = lane & 15, g = lane >> 4;
    long long e0 = wv * 8 + (long long)g * 2;
    if (e0 >= L) return;
    bool two = (e0 + 1 < L);
    int a0 = eli[e0],            b0 = eli[(long long)L + e0];
    int a1 = two ? eli[e0 + 1] : a0;
    int b1 = two ? eli[(long long)L + e0 + 1] : b0;
    const float4* XU = (const float4*)xu;
    const float4* XR = (const float4*)xr;
    float4 u0 = XU[(a0 << 4) + c];
    float4 r0 = XR[(b0 << 4) + c];
    float4 u1 = XU[(a1 << 4) + c];
    float4 r1 = XR[(b1 << 4) + c];
    float p0 = u0.x * r0.x; p0 = fmaf(u0.y, r0.y, p0); p0 = fmaf(u0.z, r0.z, p0); p0 = fmaf(u0.w, r0.w, p0);
    float p1 = u1.x * r1.x; p1 = fmaf(u1.y, r1.y, p1); p1 = fmaf(u1.z, r1.z, p1); p1 = fmaf(u1.w, r1.w, p1);
#pragma unroll
    for (int off = 1; off < 16; off <<= 1) {
        p0 += __shfl_xor(p0, off);
        p1 += __shfl_xor(p1, off);
    }
    if (c == 0) {
        out[e0] = p0;
        if (two) out[e0 + 1] = p1;
    }
}

extern "C" void kernel_launch(void* const* d_in, const int* in_sizes, int n_in,
                              void* d_out, int out_size, void* d_ws, size_t ws_size,
                              hipStream_t stream) {
    const int*   uid        = (const int*)d_in[0];
    const int*   rid        = (const int*)d_in[1];
    const float* recipe_x   = (const float*)d_in[2];
    const int*   ei         = (const int*)d_in[3];
    const int*   eli        = (const int*)d_in[4];
    const float* user_emb   = (const float*)d_in[5];
    const float* recipe_emb = (const float*)d_in[6];
    const float* lin_w      = (const float*)d_in[7];
    const float* lin_b      = (const float*)d_in[8];
    const float* Wl         = (const float*)d_in[9];
    const float* bl         = (const float*)d_in[10];
    const float* Wr         = (const float*)d_in[11];

    const int Nu = in_sizes[0], Nr = in_sizes[1];
    const int E = in_sizes[3] / 2, L = in_sizes[4] / 2;
    const int nmax = (Nu > Nr) ? Nu : Nr;
    const int W = ((nmax - 1) >> WSH) + 1;   // 196 for N=200000

    char* ws = (char*)d_ws;
    size_t off = 0;
    auto alloc = [&](size_t bytes) -> char* {
        char* p = ws + off;
        off += (bytes + 255) & ~(size_t)255;
        return p;
    };
    float* x_user   = (float*)alloc((size_t)Nu * H * 4);
    float* x_recipe = (float*)alloc((size_t)Nr * H * 4);
    // overlay: y buffers (needed from sage on) share space with bin buffers (dead by then)
    size_t ybytes  = ((size_t)Nu + Nr) * H * 4;
    size_t bbytes  = (size_t)E * 8 * 2;
    char* region   = alloc(ybytes > bbytes ? ybytes : bbytes);
    float* y_user   = (float*)region;
    float* y_recipe = (float*)(region + (size_t)Nu * H * 4);
    int2* bufS = (int2*)region;
    int2* bufD = (int2*)(region + (size_t)E * 8);
    int* rp_src  = (int*)alloc((size_t)(Nu + 1) * 4);
    int* rp_dst  = (int*)alloc((size_t)(Nr + 1) * 4);
    int* col_src = (int*)alloc((size_t)E * 4);
    int* col_dst = (int*)alloc((size_t)E * 4);
    int* winS  = (int*)alloc(MAXW * 4);      // winS..winD adjacent: one memset
    int* winD  = (int*)alloc(MAXW * 4);
    int* baseS = (int*)alloc((MAXW + 1) * 4);
    int* baseD = (int*)alloc((MAXW + 1) * 4);
    int* curS  = (int*)alloc(MAXW * 4);
    int* curD  = (int*)alloc(MAXW * 4);
    (void)ws_size; (void)n_in; (void)out_size;

    // zero window counters (ws is poisoned 0xAA)
    hipMemsetAsync(winS, 0, (size_t)2 * MAXW * 4, stream);

    // CSR build: count -> scan -> bin -> fused per-window (deg+scan+scatter)
    k_wincount<<<1024, 256, 0, stream>>>(ei, E, winS, winD);
    k_scan_win<<<1, 256, 0, stream>>>(winS, winD, baseS, baseD, curS, curD);
    k_bin<<<(E + BINCH - 1) / BINCH, 256, 0, stream>>>(ei, E, curS, curD, bufS, bufD);
    k_build_win<<<2 * W, 256, 0, stream>>>(bufS, bufD, baseS, baseD,
                                           rp_src, rp_dst, col_src, col_dst, Nu, Nr, W);

    // initial features
    k_init_x<<<(nmax + 3) / 4, 256, 0, stream>>>(uid, rid, recipe_x, user_emb, recipe_emb,
                                                 lin_w, lin_b, x_user, x_recipe, Nu, Nr);

    int nbR = (Nr + 15) / 16, nbU = (Nu + 15) / 16;
    // layer 0 (+ReLU): both directions in one launch
    k_sage2<true><<<nbR + nbU, 256, 0, stream>>>(
        x_user, x_recipe, rp_dst, col_dst, Wl + 0 * H * H, bl + 0 * H, Wr + 0 * H * H, y_recipe, Nr, nbR,
        x_recipe, x_user, rp_src, col_src, Wl + 1 * H * H, bl + 1 * H, Wr + 1 * H * H, y_user, Nu);
    // layer 1 (no ReLU)
    k_sage2<false><<<nbR + nbU, 256, 0, stream>>>(
        y_user, y_recipe, rp_dst, col_dst, Wl + 2 * H * H, bl + 2 * H, Wr + 2 * H * H, x_recipe, Nr, nbR,
        y_recipe, y_user, rp_src, col_src, Wl + 3 * H * H, bl + 3 * H, Wr + 3 * H * H, x_user, Nu);

    // classifier: 32 edges per block
    long long nblk = ((long long)L + 31) / 32;
    k_dot<<<(int)nblk, 256, 0, stream>>>(x_user, x_recipe, eli, (float*)d_out, L);
}